// Round 1
// baseline (289.855 us; speedup 1.0000x reference)
//
#include <hip/hip_runtime.h>
#include <hip/hip_cooperative_groups.h>

namespace cg = cooperative_groups;

// RMAC: x[64, 2048, 16, 16] f32 -> f[64, 14*2048] L2-normalized per batch row.
// Windows (H=W=16): l1: 16x16 -> 1 region (/256); l2: 10x10 stride 4 -> 2x2,
// rows/cols [0,10),[4,14) (/100); l3: 8x8 stride 3 -> 3x3, [0,8),[3,11),[6,14) (/64).
// Feature k (0..13) at out[b*FEAT + k*C + c].
//
// Round-4: FUSED single cooperative kernel. Each block computes its otile
// (256 channels x 14 feats), reduces its own sum-of-squares from LDS (no extra
// global traffic), publishes 1 float/block to d_ws, grid.sync(), sums the 8
// partials of its batch row, writes out ONCE already scaled. Removes the norm
// kernel's full second pass over out (7 MiB read + 7 MiB re-write + launch gap).

constexpr int C    = 2048;
constexpr int NB   = 64;
constexpr int FEAT = 14 * C;       // 28672
constexpr float EPS = 1e-12f;

constexpr int IMG_S4  = 65;           // float4 stride per image in LDS (1040 B)
constexpr int WAVE_S4 = 8 * IMG_S4;   // 8 images staged per wave per iter
constexpr int NBLK    = (NB * C) / 256;  // 512 blocks = 2 blocks/CU x 256 CUs

// Shared pool body: fills otile[14][256] with the SCALED pooled features for
// this block's 256 images. Ends with __syncthreads() so otile is ready.
__device__ __forceinline__ void rmac_pool_body(
    const float4* __restrict__ x4, float4* __restrict__ stage,
    float (* __restrict__ otile)[256], const int blockImg)
{
    const int tid  = threadIdx.x;
    const int lane = tid & 63;
    const int w    = tid >> 6;
    const int t    = lane & 7;    // image within stage
    const int o    = lane >> 3;   // row pair 0..7 (rows 2o, 2o+1)

    float4* sw = stage + w * WAVE_S4;

    #pragma unroll 1
    for (int s = 0; s < 8; ++s) {
        const int imgBase = blockImg + w * 64 + s * 8;

        // 8 perfectly-coalesced 1 KiB loads (one whole image per instruction)
        float4 v[8];
        #pragma unroll
        for (int i = 0; i < 8; ++i)
            v[i] = x4[(size_t)(imgBase + i) * 64 + lane];
        #pragma unroll
        for (int i = 0; i < 8; ++i)
            sw[i * IMG_S4 + lane] = v[i];
        // same-wave LDS RAW: in-order DS pipe + compiler lgkmcnt — no barrier needed

        float rs[14];
        #pragma unroll
        for (int k = 0; k < 14; ++k) rs[k] = 0.f;

        const float4* img = sw + t * IMG_S4 + o * 8;   // rows 2o, 2o+1
        #pragma unroll
        for (int r = 0; r < 2; ++r) {
            float4 a0 = img[r*4+0], a1 = img[r*4+1], a2 = img[r*4+2], a3 = img[r*4+3];
            float vv[16] = {a0.x,a0.y,a0.z,a0.w, a1.x,a1.y,a1.z,a1.w,
                            a2.x,a2.y,a2.z,a2.w, a3.x,a3.y,a3.z,a3.w};
            float pref[17]; pref[0] = 0.f;
            #pragma unroll
            for (int k2 = 0; k2 < 16; ++k2) pref[k2+1] = pref[k2] + vv[k2];

            const float full = pref[16];
            const float c20  = pref[10];             // cols [0,10)
            const float c21  = pref[14] - pref[4];   // cols [4,14)
            const float c30  = pref[8];              // cols [0,8)
            const float c31  = pref[11] - pref[3];   // cols [3,11)
            const float c32  = pref[14] - pref[6];   // cols [6,14)

            const int y = o * 2 + r;                 // lane-dependent -> predicated adds
            bool m;
            rs[0] += full;
            m = (y < 10);          rs[1]  += m ? c20 : 0.f; rs[2]  += m ? c21 : 0.f;
            m = (y >= 4 && y < 14);rs[3]  += m ? c20 : 0.f; rs[4]  += m ? c21 : 0.f;
            m = (y < 8);           rs[5]  += m ? c30 : 0.f; rs[6]  += m ? c31 : 0.f; rs[7]  += m ? c32 : 0.f;
            m = (y >= 3 && y < 11);rs[8]  += m ? c30 : 0.f; rs[9]  += m ? c31 : 0.f; rs[10] += m ? c32 : 0.f;
            m = (y >= 6 && y < 14);rs[11] += m ? c30 : 0.f; rs[12] += m ? c31 : 0.f; rs[13] += m ? c32 : 0.f;
        }

        // combine the 8 row-pairs (lanes t, t+8, ..., t+56)
        #pragma unroll
        for (int k = 0; k < 14; ++k) {
            rs[k] += __shfl_xor(rs[k], 8, 64);
            rs[k] += __shfl_xor(rs[k], 16, 64);
            rs[k] += __shfl_xor(rs[k], 32, 64);
        }

        const int col = w * 64 + s * 8 + t;
        #pragma unroll
        for (int k = 0; k < 14; ++k) {
            const float sc = (k == 0) ? (1.f/256.f) : (k < 5 ? (1.f/100.f) : (1.f/64.f));
            if ((k & 7) == o) otile[k][col] = rs[k] * sc;   // o-groups split the 14 writes
        }
    }
    __syncthreads();   // otile complete for whole block
}

// -------- fused cooperative kernel: pool + row-L2-normalize in one pass -----
__global__ __launch_bounds__(256, 2) void rmac_fused_kernel(
    const float4* __restrict__ x4, float* __restrict__ out,
    float* __restrict__ ws)
{
    __shared__ float4 stage[4 * WAVE_S4];   // 33280 B
    __shared__ float  otile[14][256];       // 14336 B
    __shared__ float  red[4];

    const int tid      = threadIdx.x;
    const int blockImg = blockIdx.x * 256;

    rmac_pool_body(x4, stage, otile, blockImg);

    // Block-partial sum of squares straight from LDS (values already scaled).
    float ssl = 0.f;
    #pragma unroll
    for (int k = 0; k < 14; ++k) { const float v = otile[k][tid]; ssl += v * v; }
    #pragma unroll
    for (int off = 32; off; off >>= 1) ssl += __shfl_down(ssl, off, 64);
    if ((tid & 63) == 0) red[tid >> 6] = ssl;
    __syncthreads();
    if (tid == 0) {
        ws[blockIdx.x] = red[0] + red[1] + red[2] + red[3];
        __threadfence();                         // device-scope release of partial
    }

    cg::this_grid().sync();                      // all 512 blocks (2/CU) resident

    // Row total = 8 consecutive block partials (blocks of one b are contiguous).
    const int b = blockIdx.x >> 3;               // 8 blocks per batch row
    const volatile float* wsv = ws;
    float tot = 0.f;
    #pragma unroll
    for (int j = 0; j < 8; ++j) tot += wsv[(b << 3) + j];
    const float s = 1.f / fmaxf(sqrtf(tot), EPS);

    // Single, already-scaled, coalesced write of this block's 256 channels.
    const int c = (blockImg + tid) & (C - 1);
    #pragma unroll
    for (int k = 0; k < 14; ++k)
        out[(size_t)b * FEAT + (size_t)k * C + c] = otile[k][tid] * s;
}

// ---------------- fallback two-kernel path (if cooperative launch fails) ----
__global__ __launch_bounds__(256, 2) void rmac_pool_kernel(
    const float4* __restrict__ x4, float* __restrict__ out)
{
    __shared__ float4 stage[4 * WAVE_S4];
    __shared__ float  otile[14][256];

    const int tid      = threadIdx.x;
    const int blockImg = blockIdx.x * 256;

    rmac_pool_body(x4, stage, otile, blockImg);

    const int img = blockImg + tid;
    const int b   = img >> 11;
    const int c   = img & (C - 1);
    #pragma unroll
    for (int k = 0; k < 14; ++k)
        out[(size_t)b * FEAT + (size_t)k * C + c] = otile[k][tid];
}

__global__ __launch_bounds__(1024) void rmac_norm_kernel(float* __restrict__ out)
{
    const int b   = blockIdx.x;
    const int tid = threadIdx.x;
    float4* row = reinterpret_cast<float4*>(out + (size_t)b * FEAT);  // 7168 float4

    float4 v[7];
    float ss = 0.f;
    #pragma unroll
    for (int j = 0; j < 7; ++j) {
        v[j] = row[tid + j * 1024];
        ss += v[j].x*v[j].x + v[j].y*v[j].y + v[j].z*v[j].z + v[j].w*v[j].w;
    }

    #pragma unroll
    for (int off = 32; off; off >>= 1) ss += __shfl_down(ss, off, 64);
    __shared__ float red[16];
    const int lane = tid & 63, w = tid >> 6;
    if (lane == 0) red[w] = ss;
    __syncthreads();
    float tot = 0.f;
    #pragma unroll
    for (int i = 0; i < 16; ++i) tot += red[i];   // broadcast reads, no conflicts

    const float s = 1.f / fmaxf(sqrtf(tot), EPS);
    #pragma unroll
    for (int j = 0; j < 7; ++j) {
        v[j].x *= s; v[j].y *= s; v[j].z *= s; v[j].w *= s;
        row[tid + j * 1024] = v[j];
    }
}

extern "C" void kernel_launch(void* const* d_in, const int* in_sizes, int n_in,
                              void* d_out, int out_size, void* d_ws, size_t ws_size,
                              hipStream_t stream)
{
    const float4* x4 = (const float4*)d_in[0];
    float* out       = (float*)d_out;
    float* ws        = (float*)d_ws;

    bool fused_ok = (ws != nullptr) && (ws_size >= NBLK * sizeof(float));
    if (fused_ok) {
        void* kargs[] = { (void*)&x4, (void*)&out, (void*)&ws };
        hipError_t err = hipLaunchCooperativeKernel(
            (const void*)rmac_fused_kernel, dim3(NBLK), dim3(256),
            kargs, 0, stream);
        if (err == hipSuccess) return;
        (void)hipGetLastError();   // clear, fall through to two-kernel path
    }

    rmac_pool_kernel<<<NBLK, 256, 0, stream>>>(x4, out);
    rmac_norm_kernel<<<NB, 1024, 0, stream>>>(out);
}

// Round 3
// 195.610 us; speedup vs baseline: 1.4818x; 1.4818x over previous
//
#include <hip/hip_runtime.h>

// RMAC: x[64, 2048, 16, 16] f32 -> f[64, 14*2048] L2-normalized per batch row.
// Windows (H=W=16): l1: 16x16 -> 1 region (/256); l2: 10x10 stride 4 -> 2x2,
// rows/cols [0,10),[4,14) (/100); l3: 8x8 stride 3 -> 3x3, [0,8),[3,11),[6,14) (/64).
// Feature k (0..13) at out[b*FEAT + k*C + c].
//
// Round-6: resubmit of round-5 (bench infra failed; kernel never ran).
// Structure: round-0 two-kernel pipeline + per-block ss partial in ws so the
// scale pass runs on 512 blocks (all 256 CUs) instead of 64 blocks (64 CUs).
// Norm/scale traffic (14.3 MB) moves at full-chip BW: ~9 us -> ~3 us.

constexpr int C    = 2048;
constexpr int NB   = 64;
constexpr int FEAT = 14 * C;       // 28672
constexpr float EPS = 1e-12f;

constexpr int IMG_S4  = 65;           // float4 stride per image in LDS (1040 B)
constexpr int WAVE_S4 = 8 * IMG_S4;   // 8 images staged per wave per iter
constexpr int NBLK    = (NB * C) / 256;  // 512 blocks = 2/CU x 256 CUs

__global__ __launch_bounds__(256, 2) void rmac_pool_kernel(
    const float4* __restrict__ x4, float* __restrict__ out,
    float* __restrict__ ws)
{
    __shared__ float4 stage[4 * WAVE_S4];   // 33280 B
    __shared__ float  otile[14][256];       // 14336 B
    __shared__ float  red[4];

    const int tid  = threadIdx.x;
    const int lane = tid & 63;
    const int w    = tid >> 6;
    const int t    = lane & 7;    // image within stage
    const int o    = lane >> 3;   // row pair 0..7 (rows 2o, 2o+1)

    const int blockImg = blockIdx.x * 256;
    float4* sw = stage + w * WAVE_S4;

    #pragma unroll 1
    for (int s = 0; s < 8; ++s) {
        const int imgBase = blockImg + w * 64 + s * 8;

        // 8 perfectly-coalesced 1 KiB loads (one whole image per instruction)
        float4 v[8];
        #pragma unroll
        for (int i = 0; i < 8; ++i)
            v[i] = x4[(size_t)(imgBase + i) * 64 + lane];
        #pragma unroll
        for (int i = 0; i < 8; ++i)
            sw[i * IMG_S4 + lane] = v[i];
        // same-wave LDS RAW: in-order DS pipe + compiler lgkmcnt — no barrier needed

        float rs[14];
        #pragma unroll
        for (int k = 0; k < 14; ++k) rs[k] = 0.f;

        const float4* img = sw + t * IMG_S4 + o * 8;   // rows 2o, 2o+1
        #pragma unroll
        for (int r = 0; r < 2; ++r) {
            float4 a0 = img[r*4+0], a1 = img[r*4+1], a2 = img[r*4+2], a3 = img[r*4+3];
            float vv[16] = {a0.x,a0.y,a0.z,a0.w, a1.x,a1.y,a1.z,a1.w,
                            a2.x,a2.y,a2.z,a2.w, a3.x,a3.y,a3.z,a3.w};
            float pref[17]; pref[0] = 0.f;
            #pragma unroll
            for (int k2 = 0; k2 < 16; ++k2) pref[k2+1] = pref[k2] + vv[k2];

            const float full = pref[16];
            const float c20  = pref[10];             // cols [0,10)
            const float c21  = pref[14] - pref[4];   // cols [4,14)
            const float c30  = pref[8];              // cols [0,8)
            const float c31  = pref[11] - pref[3];   // cols [3,11)
            const float c32  = pref[14] - pref[6];   // cols [6,14)

            const int y = o * 2 + r;                 // lane-dependent -> predicated adds
            bool m;
            rs[0] += full;
            m = (y < 10);          rs[1]  += m ? c20 : 0.f; rs[2]  += m ? c21 : 0.f;
            m = (y >= 4 && y < 14);rs[3]  += m ? c20 : 0.f; rs[4]  += m ? c21 : 0.f;
            m = (y < 8);           rs[5]  += m ? c30 : 0.f; rs[6]  += m ? c31 : 0.f; rs[7]  += m ? c32 : 0.f;
            m = (y >= 3 && y < 11);rs[8]  += m ? c30 : 0.f; rs[9]  += m ? c31 : 0.f; rs[10] += m ? c32 : 0.f;
            m = (y >= 6 && y < 14);rs[11] += m ? c30 : 0.f; rs[12] += m ? c31 : 0.f; rs[13] += m ? c32 : 0.f;
        }

        // combine the 8 row-pairs (lanes t, t+8, ..., t+56)
        #pragma unroll
        for (int k = 0; k < 14; ++k) {
            rs[k] += __shfl_xor(rs[k], 8, 64);
            rs[k] += __shfl_xor(rs[k], 16, 64);
            rs[k] += __shfl_xor(rs[k], 32, 64);
        }

        const int col = w * 64 + s * 8 + t;
        #pragma unroll
        for (int k = 0; k < 14; ++k) {
            const float sc = (k == 0) ? (1.f/256.f) : (k < 5 ? (1.f/100.f) : (1.f/64.f));
            if ((k & 7) == o) otile[k][col] = rs[k] * sc;   // o-groups split the 14 writes
        }
    }
    __syncthreads();

    // coalesced feature stores (block covers 256 consecutive c of one b),
    // fused with the block's sum-of-squares partial (values already in regs)
    const int img = blockImg + tid;
    const int b   = img >> 11;
    const int c   = img & (C - 1);
    float ssl = 0.f;
    #pragma unroll
    for (int k = 0; k < 14; ++k) {
        const float v = otile[k][tid];
        out[(size_t)b * FEAT + (size_t)k * C + c] = v;
        ssl += v * v;
    }
    #pragma unroll
    for (int off = 32; off; off >>= 1) ssl += __shfl_down(ssl, off, 64);
    if ((tid & 63) == 0) red[tid >> 6] = ssl;
    __syncthreads();
    if (tid == 0 && ws != nullptr)
        ws[blockIdx.x] = red[0] + red[1] + red[2] + red[3];
}

// 512 blocks (8 per batch row) — full-chip BW for the scale pass.
// Row total ss = sum of the row's 8 block partials from ws (kernel-boundary
// on the stream guarantees visibility; L2-hot broadcast reads).
__global__ __launch_bounds__(128) void rmac_scale_kernel(
    float* __restrict__ out, const float* __restrict__ ws)
{
    const int g     = blockIdx.x;        // 0..511
    const int b     = g >> 3;
    const int chunk = g & 7;

    float tot = 0.f;
    #pragma unroll
    for (int j = 0; j < 8; ++j) tot += ws[(b << 3) + j];
    const float s = 1.f / fmaxf(sqrtf(tot), EPS);

    // 7168 float4 per row; this block owns 896 of them; 128 threads x 7 each.
    float4* row = reinterpret_cast<float4*>(out + (size_t)b * FEAT) + chunk * 896;
    const int tid = threadIdx.x;
    #pragma unroll
    for (int j = 0; j < 7; ++j) {
        float4 v = row[tid + j * 128];
        v.x *= s; v.y *= s; v.z *= s; v.w *= s;
        row[tid + j * 128] = v;
    }
}

// Fallback (ws unavailable): recompute row ss, 64 blocks x 1024 threads.
__global__ __launch_bounds__(1024) void rmac_norm_kernel(float* __restrict__ out)
{
    const int b   = blockIdx.x;
    const int tid = threadIdx.x;
    float4* row = reinterpret_cast<float4*>(out + (size_t)b * FEAT);  // 7168 float4

    float4 v[7];
    float ss = 0.f;
    #pragma unroll
    for (int j = 0; j < 7; ++j) {
        v[j] = row[tid + j * 1024];
        ss += v[j].x*v[j].x + v[j].y*v[j].y + v[j].z*v[j].z + v[j].w*v[j].w;
    }

    #pragma unroll
    for (int off = 32; off; off >>= 1) ss += __shfl_down(ss, off, 64);
    __shared__ float red[16];
    const int lane = tid & 63, w = tid >> 6;
    if (lane == 0) red[w] = ss;
    __syncthreads();
    float tot = 0.f;
    #pragma unroll
    for (int i = 0; i < 16; ++i) tot += red[i];   // broadcast reads, no conflicts

    const float s = 1.f / fmaxf(sqrtf(tot), EPS);
    #pragma unroll
    for (int j = 0; j < 7; ++j) {
        v[j].x *= s; v[j].y *= s; v[j].z *= s; v[j].w *= s;
        row[tid + j * 1024] = v[j];
    }
}

extern "C" void kernel_launch(void* const* d_in, const int* in_sizes, int n_in,
                              void* d_out, int out_size, void* d_ws, size_t ws_size,
                              hipStream_t stream)
{
    const float4* x4 = (const float4*)d_in[0];
    float* out       = (float*)d_out;
    float* ws        = (float*)d_ws;

    const bool ws_ok = (ws != nullptr) && (ws_size >= NBLK * sizeof(float));

    rmac_pool_kernel<<<NBLK, 256, 0, stream>>>(x4, out, ws_ok ? ws : nullptr);
    if (ws_ok)
        rmac_scale_kernel<<<NBLK, 128, 0, stream>>>(out, ws);
    else
        rmac_norm_kernel<<<NB, 1024, 0, stream>>>(out);
}